// Round 4
// baseline (154.433 us; speedup 1.0000x reference)
//
#include <hip/hip_runtime.h>

// Problem constants (fixed by setup_inputs):
//   tensor  [B=8, C=64, H=256, W=256] float32
//   centers [B=8, N=512, 2] int32 (y, x) in [0, 256)
//   patch 16x16, pad 8 -> out[b][n][c][i][j] = in-bounds ? tensor[b][c][cy+i-8][cx+j-8] : 0
//   out     [B=8, N=512, C=64, 16, 16] float32 (256 MB)
//
// Design (round 4): identical to round 3 EXCEPT stores are normal write-back
// (round 3's nontemporal stores capped the write stream at ~2.2 TB/s; L2
// write-combining should lift that). One block per (b, n, channel-group-of-8),
// grid = 32768; g = blockIdx.x & 7 pins plane set [8g, 8g+8) to XCD g
// (round-1/3 evidence: FETCH 65-71 MB with this partitioning vs 302 MB
// without). Each block writes an 8 KB contiguous output chunk: 2 dwordx4
// stores per thread; reads are 4 predicated dword loads per lane, one wave
// covers one channel's 16x16 patch per pass.

#define B_ 8
#define C_ 64
#define H_ 256
#define W_ 256
#define N_ 512

typedef float f32x4 __attribute__((ext_vector_type(4)));

__global__ __launch_bounds__(256) void patch_extract_kernel(
    const float* __restrict__ in,
    const int* __restrict__ centers,
    float* __restrict__ out)
{
    const int blk = blockIdx.x;
    const int g   = blk & 7;          // channel group -> XCD (round-robin)
    const int bn  = blk >> 3;         // b*N + n
    const int b   = bn >> 9;          // bn / 512
    const int t   = threadIdx.x;

    // Block-uniform -> scalar broadcast loads.
    const int cy = centers[(bn << 1) + 0];
    const int cx = centers[(bn << 1) + 1];

    // Base of this block's 8 channel planes.
    const float* inb = in + ((long long)b * (C_ * H_ * W_)) + (((long long)g * 8) << 16);
    // Base of this block's contiguous 8 KB output chunk.
    float* outc = out + ((long long)bn << 14) + (((long long)g * 8) << 8);

    #pragma unroll
    for (int p = 0; p < 2; ++p) {
        const int q       = (p << 8) + t;   // quad index 0..511 within chunk
        const int c_local = q >> 6;         // 0..7 (wave-uniform)
        const int rem     = q & 63;
        const int i       = rem >> 2;       // patch row 0..15
        const int j0      = (rem & 3) << 2; // patch col start: 0,4,8,12

        const int y   = cy + i - 8;
        const int x0  = cx + j0 - 8;
        const bool yin = (unsigned)y < (unsigned)H_;

        const float* row = inb + ((long long)c_local << 16) + (long long)y * W_;

        f32x4 v;
        #pragma unroll
        for (int l = 0; l < 4; ++l) {
            const int x = x0 + l;
            float f = 0.0f;
            if (yin && (unsigned)x < (unsigned)W_) f = row[x];
            v[l] = f;
        }
        // Normal write-back store (NT store capped write BW at ~2.2 TB/s).
        *(f32x4*)(outc + ((long long)q << 2)) = v;
    }
}

extern "C" void kernel_launch(void* const* d_in, const int* in_sizes, int n_in,
                              void* d_out, int out_size, void* d_ws, size_t ws_size,
                              hipStream_t stream) {
    const float* tensor  = (const float*)d_in[0];
    const int*   centers = (const int*)d_in[1];
    float*       out     = (float*)d_out;

    patch_extract_kernel<<<B_ * N_ * 8, 256, 0, stream>>>(tensor, centers, out);
}

// Round 5
// 60.009 us; speedup vs baseline: 2.5735x; 2.5735x over previous
//
#include <hip/hip_runtime.h>

// Problem constants (fixed by setup_inputs):
//   tensor  [B=8, C=64, H=256, W=256] float32
//   centers [B=8, N=512, 2] int32 (y, x) in [0, 256)
//   patch 16x16, pad 8 -> out[b][n][c][i][j] = in-bounds ? tensor[b][c][cy+i-8][cx+j-8] : 0
//   out     [B=8, N=512, C=64, 16, 16] float32 (256 MB)
//
// Design (round 5): R3 structure (block per (b,n,channel-group-of-8), grid
// 32768, g = blockIdx.x & 7 pins planes [8g,8g+8) to XCD g -> FETCH ~65MB;
// NT dwordx4 stores -- R4 proved write-back is slower). ONE change vs R3:
// reads collapse from 4 predicated dword loads (each instruction touched all
// 16 patch rows -> 4x redundant L1 segment transactions) to a single
// predicated dwordx4 per lane, so one wave instruction covers the whole
// channel-patch at the distinct-segment minimum. OOB columns handled by
// clamping the load address into the row ([0,252], always safe) plus a
// per-element cndmask select; OOB rows predicate the load entirely.

#define B_ 8
#define C_ 64
#define H_ 256
#define W_ 256
#define N_ 512

typedef float f32x4 __attribute__((ext_vector_type(4)));

__global__ __launch_bounds__(256) void patch_extract_kernel(
    const float* __restrict__ in,
    const int* __restrict__ centers,
    float* __restrict__ out)
{
    const int blk = blockIdx.x;
    const int g   = blk & 7;          // channel group -> XCD (round-robin)
    const int bn  = blk >> 3;         // b*N + n
    const int b   = bn >> 9;          // bn / 512
    const int t   = threadIdx.x;

    // Block-uniform -> scalar broadcast loads.
    const int cy = centers[(bn << 1) + 0];
    const int cx = centers[(bn << 1) + 1];

    const int rem = t & 63;           // lane
    const int i   = rem >> 2;         // patch row 0..15
    const int j0  = (rem & 3) << 2;   // patch col start: 0,4,8,12
    const int wv  = t >> 6;           // wave id 0..3

    const int y    = cy + i - 8;
    const bool yin = (unsigned)y < (unsigned)H_;
    const int x0   = cx + j0 - 8;                 // in [-8, 259]
    const int xc   = min(max(x0, 0), W_ - 4);     // clamped load col, always safe
    const int s    = x0 - xc;                     // element shift

    // Base of this block's 8 channel planes.
    const float* inb = in + ((long long)b * (C_ * H_ * W_)) + (((long long)g * 8) << 16);
    // Base of this block's contiguous 8 KB output chunk.
    float* outc = out + ((long long)bn << 14) + (((long long)g * 8) << 8);

    #pragma unroll
    for (int p = 0; p < 2; ++p) {
        const int c_local = (p << 2) + wv;        // wave-uniform channel
        const float* rowp = inb + ((long long)c_local << 16) + (long long)y * W_ + xc;

        f32x4 ld = {0.0f, 0.0f, 0.0f, 0.0f};
        if (yin) ld = *(const f32x4*)rowp;        // single dwordx4 (4B-aligned ok)

        f32x4 v;
        #pragma unroll
        for (int k = 0; k < 4; ++k) {
            const int col = x0 + k;
            const int idx = s + k;                // = col - xc; in [0,3] when ok
            float f = ld[0];
            f = (idx == 1) ? ld[1] : f;
            f = (idx == 2) ? ld[2] : f;
            f = (idx == 3) ? ld[3] : f;
            const bool ok = yin && (unsigned)col < (unsigned)W_;
            v[k] = ok ? f : 0.0f;
        }

        // NT store: output never re-read (R4 showed write-back is slower).
        __builtin_nontemporal_store(v, (f32x4*)(outc + ((long long)((p << 8) + t) << 2)));
    }
}

extern "C" void kernel_launch(void* const* d_in, const int* in_sizes, int n_in,
                              void* d_out, int out_size, void* d_ws, size_t ws_size,
                              hipStream_t stream) {
    const float* tensor  = (const float*)d_in[0];
    const int*   centers = (const int*)d_in[1];
    float*       out     = (float*)d_out;

    patch_extract_kernel<<<B_ * N_ * 8, 256, 0, stream>>>(tensor, centers, out);
}

// Round 6
// 59.977 us; speedup vs baseline: 2.5749x; 1.0005x over previous
//
#include <hip/hip_runtime.h>

// Problem constants (fixed by setup_inputs):
//   tensor  [B=8, C=64, H=256, W=256] float32
//   centers [B=8, N=512, 2] int32 (y, x) in [0, 256)
//   patch 16x16, pad 8 -> out[b][n][c][i][j] = in-bounds ? tensor[b][c][cy+i-8][cx+j-8] : 0
//   out     [B=8, N=512, C=64, 16, 16] float32 (256 MB)
//
// Design (round 6): R5 structure (single dwordx4 read per lane per
// channel-patch, clamp+select OOB handling, NT dwordx4 stores, g=blk&7 XCD
// pinning) with ONE change: 2 patches per block (grid 16384) and fully
// unconditional loads (y clamped like x; zeros via per-element select).
// Gives each thread 4 independent loads + 4 independent NT stores with no
// exec-mask divergence -> tests whether the residual 60-vs-48us gap is
// memory-issue-limited or HBM mixed-stream-drain-limited.
//   bn0 = 2*pr is even and bn1 = bn0+1, so a pair never straddles a batch
//   boundary (512 | batch stride).

#define B_ 8
#define C_ 64
#define H_ 256
#define W_ 256
#define N_ 512

typedef float f32x4 __attribute__((ext_vector_type(4)));

__global__ __launch_bounds__(256) void patch_extract_kernel(
    const float* __restrict__ in,
    const int* __restrict__ centers,
    float* __restrict__ out)
{
    const int blk = blockIdx.x;
    const int g   = blk & 7;          // channel group -> XCD (round-robin)
    const int pr  = blk >> 3;         // patch-pair index 0..2047
    const int bn0 = pr << 1;          // first patch (even)
    const int b   = bn0 >> 9;         // batch (same for both patches)
    const int t   = threadIdx.x;

    const int rem = t & 63;           // lane
    const int i   = rem >> 2;         // patch row 0..15
    const int j0  = (rem & 3) << 2;   // patch col start: 0,4,8,12
    const int wv  = t >> 6;           // wave id 0..3

    // Base of this block's 8 channel planes.
    const float* inb = in + ((long long)b * (C_ * H_ * W_)) + (((long long)g * 8) << 16);

    int cy[2], cx[2], x0[2], xc[2], y[2], yc[2];
    #pragma unroll
    for (int u = 0; u < 2; ++u) {
        cy[u] = centers[((bn0 + u) << 1) + 0];
        cx[u] = centers[((bn0 + u) << 1) + 1];
        y[u]  = cy[u] + i - 8;
        yc[u] = min(max(y[u], 0), H_ - 1);        // clamped row, always safe
        x0[u] = cx[u] + j0 - 8;                   // in [-8, 259]
        xc[u] = min(max(x0[u], 0), W_ - 4);       // clamped col, always safe
    }

    // Issue all 4 independent dwordx4 loads unconditionally (no exec-mask
    // divergence; OOB handled by the select below).
    f32x4 ld[2][2];
    #pragma unroll
    for (int u = 0; u < 2; ++u) {
        #pragma unroll
        for (int p = 0; p < 2; ++p) {
            const int c_local = (p << 2) + wv;    // wave-uniform channel
            ld[u][p] = *(const f32x4*)(inb + ((long long)c_local << 16)
                                           + (long long)yc[u] * W_ + xc[u]);
        }
    }

    #pragma unroll
    for (int u = 0; u < 2; ++u) {
        const bool yin = (unsigned)y[u] < (unsigned)H_;
        const int  s   = x0[u] - xc[u];
        float* outc = out + ((long long)(bn0 + u) << 14) + (((long long)g * 8) << 8);

        #pragma unroll
        for (int p = 0; p < 2; ++p) {
            f32x4 v;
            #pragma unroll
            for (int k = 0; k < 4; ++k) {
                const int col = x0[u] + k;
                const int idx = s + k;            // in [0,3] when in-bounds
                float f = ld[u][p][0];
                f = (idx == 1) ? ld[u][p][1] : f;
                f = (idx == 2) ? ld[u][p][2] : f;
                f = (idx == 3) ? ld[u][p][3] : f;
                const bool ok = yin && (unsigned)col < (unsigned)W_;
                v[k] = ok ? f : 0.0f;
            }
            // NT store: output never re-read (R4 showed write-back is slower).
            __builtin_nontemporal_store(v, (f32x4*)(outc + ((long long)((p << 8) + t) << 2)));
        }
    }
}

extern "C" void kernel_launch(void* const* d_in, const int* in_sizes, int n_in,
                              void* d_out, int out_size, void* d_ws, size_t ws_size,
                              hipStream_t stream) {
    const float* tensor  = (const float*)d_in[0];
    const int*   centers = (const int*)d_in[1];
    float*       out     = (float*)d_out;

    patch_extract_kernel<<<B_ * N_ * 8 / 2, 256, 0, stream>>>(tensor, centers, out);
}